// Round 11
// baseline (183.510 us; speedup 1.0000x reference)
//
#include <hip/hip_runtime.h>
#include <hip/hip_fp16.h>
#include <math.h>

// ---------------------------------------------------------------------------
// Spherical CNN regression forward (MAXL=3, 2 layers, TAU_IN=16, TAU_H=32).
// 3-launch pipeline, NO cooperative launch, NO cross-block deps:
//   k_wt:      realified f16 weights, MFMA-fragment-tiled + col-permuted
//   k_layer<0>: input matmul+norm -> HA ; CG+GEMM (block-local frags) -> HB
//   k_layer<1>: norm ; CG+GEMM -> HA ; final norms + MLP -> out
// Block = 16 elements: A rows (16*nM) = exactly nM MFMA frags, block-local.
// Per pair pl: CG (compile-time-unrolled, register hv) -> LDS A-stage
// (verified fragment layout) -> barrier -> MFMA (WT from global) -> barrier.
// ws layout: [WT 557056 B][HA B*2048 B][HB B*2048 B]
// ---------------------------------------------------------------------------

typedef _Float16 f16x8 __attribute__((ext_vector_type(8)));
typedef float f32x4 __attribute__((ext_vector_type(4)));

constexpr int kPS[5] = {0, 4, 13, 24, 34};
constexpr unsigned char kP1[34] = {
    0, 1, 2, 3,
    0, 1, 1, 1, 2, 2, 2, 3, 3,
    0, 1, 1, 1, 2, 2, 2, 2, 3, 3, 3,
    0, 1, 1, 2, 2, 2, 3, 3, 3, 3};
constexpr unsigned char kP2[34] = {
    0, 1, 2, 3,
    1, 0, 1, 2, 1, 2, 3, 2, 3,
    2, 1, 2, 3, 0, 1, 2, 3, 1, 2, 3,
    3, 2, 3, 1, 2, 3, 0, 1, 2, 3};
constexpr int kCGCoff[5] = {0, 28, 217, 602, 1092};
constexpr int kKp[4] = {256, 576, 704, 640};         // K' = 2*NP*32 per L
constexpr int kWToff[4] = {0, 16384, 53248, 98304};  // half offsets within a layer
#define WT_LAYER 139264                               // halves per layer
#define CGC_TOTAL 1092

// ---------------- compile-time compact CG table ----------------------------
constexpr double cfact(int n) {
    double r = 1.0;
    for (int i = 2; i <= n; ++i) r *= (double)i;
    return r;
}
constexpr double csqrt(double x) {
    double g = (x > 1.0) ? x : 1.0;
    for (int it = 0; it < 64; ++it) g = 0.5 * (g + x / g);
    return g;
}
constexpr double cg_coef(int l1, int l2, int L, int m1, int m2) {
    int M = m1 + m2;
    double pre = csqrt((2.0 * L + 1.0) * cfact(l1 + l2 - L) * cfact(l1 - l2 + L) *
                       cfact(-l1 + l2 + L) / cfact(l1 + l2 + L + 1));
    pre *= csqrt(cfact(L + M) * cfact(L - M) * cfact(l1 - m1) * cfact(l1 + m1) *
                 cfact(l2 - m2) * cfact(l2 + m2));
    double s = 0.0;
    for (int k = 0; k <= l1 + l2 - L; ++k) {
        int u2 = l1 - m1 - k, u3 = l2 + m2 - k;
        int u4 = L - l2 + m1 + k, u5 = L - l1 - m2 + k;
        if (u2 < 0 || u3 < 0 || u4 < 0 || u5 < 0) continue;
        double d = cfact(k) * cfact(l1 + l2 - L - k) * cfact(u2) * cfact(u3) *
                   cfact(u4) * cfact(u5);
        s += ((k & 1) ? -1.0 : 1.0) / d;
    }
    return pre * s;
}
struct CGCTable {
    float v[CGC_TOTAL];
};
constexpr CGCTable makeCGC() {
    CGCTable T{};
    for (int t = 0; t < CGC_TOTAL; ++t) {
        int L = 0;
        while (t >= kCGCoff[L + 1]) ++L;
        int rloc = t - kCGCoff[L];
        int r = rloc / 7, i = rloc % 7;
        int nM = 2 * L + 1;
        int pl = r / nM, M = r % nM;
        int l1 = kP1[kPS[L] + pl], l2 = kP2[kPS[L] + pl];
        float val = 0.0f;
        int j = (M - L) - (i - l1) + l2;
        if (i <= 2 * l1 && j >= 0 && j <= 2 * l2)
            val = (float)cg_coef(l1, l2, L, i - l1, j - l2);
        T.v[t] = val;
    }
    return T;
}
constexpr CGCTable kCGC_CE = makeCGC();

// ---------------- params ----------------------------------------------------
struct KParams {
    const float *p0, *p1, *p2, *p3;
    const float *Wi0, *Wi1, *Wi2, *Wi3;
    const float *h00, *h01, *h02, *h03, *h10, *h11, *h12, *h13;
    const float *W1, *b1, *W2, *b2;
    __half* WT;
    __half2 *HA, *HB;
    float* out;
    int B;
};

union ShU4 {
    struct {
        float2 stg[4][256];
        float2 hid[4][16][32];
    } in;
    float shv[4][392];
};

// ---------------- k_wt: WT realification into tiled layout (verified) ------
__global__ void __launch_bounds__(256) k_wt(
    const float* __restrict__ h00, const float* __restrict__ h01,
    const float* __restrict__ h02, const float* __restrict__ h03,
    const float* __restrict__ h10, const float* __restrict__ h11,
    const float* __restrict__ h12, const float* __restrict__ h13,
    __half* __restrict__ WT) {
    int t = blockIdx.x * 256 + threadIdx.x;  // [0, 2*WT_LAYER)
    int layer = t / WT_LAYER, rem = t % WT_LAYER;
    int L;
    if (rem < 16384) L = 0;
    else if (rem < 53248) L = 1;
    else if (rem < 98304) L = 2;
    else L = 3;
    int rem2 = rem - kWToff[L];
    int KT = kKp[L] / 32;
    int tile = rem2 >> 9, within = rem2 & 511;
    int lane = within >> 3, e8 = within & 7;
    int nt = tile / KT, kt = tile - nt * KT;
    int nr = lane & 15, kb = lane >> 4;
    int np = 2 * nr + (nt & 1) + 32 * (nt >> 1);  // col-perm
    int kp = kt * 32 + kb * 8 + e8;
    int q = kp >> 1, s = kp & 1, cW = np >> 1, tt = np & 1;
    const float* W = (layer == 0) ? (L == 0 ? h00 : L == 1 ? h01 : L == 2 ? h02 : h03)
                                  : (L == 0 ? h10 : L == 1 ? h11 : L == 2 ? h12 : h13);
    float wr = W[(q * 32 + cW) * 2], wi = W[(q * 32 + cW) * 2 + 1];
    float v = (tt == 0) ? (s == 0 ? wr : -wi) : (s == 0 ? wi : wr);
    WT[t] = __float2half(v);
}

// ---------------- input pass (4 elems per pass, verified body) -------------
__device__ __forceinline__ void input_pass(const KParams& p, int blk, int vb, int tid,
                                           ShU4& sh) {
    const int h = tid >> 7, t = tid & 127;
    const int b = blk * 16 + vb * 4 + h;

    for (int idx = t; idx < 256; idx += 128) {
        int slot = idx >> 4, k = idx & 15;
        int l = (slot >= 9) + (slot >= 4) + (slot >= 1);
        int m = slot - l * l;
        const float* src = (l == 0) ? p.p0 : (l == 1) ? p.p1 : (l == 2) ? p.p2 : p.p3;
        src += ((size_t)(b * (2 * l + 1) + m) * 16 + k) * 2;
        sh.in.stg[h][idx] = make_float2(src[0], src[1]);
    }
    __syncthreads();

#pragma unroll
    for (int r = 0; r < 4; ++r) {
        int oi = t + 128 * r;
        int slot = oi >> 5, c = oi & 31;
        int l = (slot >= 9) + (slot >= 4) + (slot >= 1);
        const float* W = (l == 0) ? p.Wi0 : (l == 1) ? p.Wi1 : (l == 2) ? p.Wi2 : p.Wi3;
        const float2* prow = &sh.in.stg[h][slot * 16];
        float2 acc = make_float2(0.f, 0.f);
        for (int k = 0; k < 16; ++k) {
            float2 a = prow[k];
            float2 w = *(const float2*)(W + (k * 32 + c) * 2);
            acc.x += a.x * w.x - a.y * w.y;
            acc.y += a.x * w.y + a.y * w.x;
        }
        sh.in.hid[h][slot][c] = acc;
    }
    __syncthreads();

    {
        int l = t >> 5, c = t & 31;
        int off = l * l, n = 2 * l + 1;
        float s = 0.f;
        for (int m = 0; m < n; ++m) {
            float2 v = sh.in.hid[h][off + m][c];
            s += v.x * v.x + v.y * v.y;
        }
        float inv = 1.0f / sqrtf(s);
        for (int m = 0; m < n; ++m) {
            float2 v = sh.in.hid[h][off + m][c];
            sh.in.hid[h][off + m][c] = make_float2(v.x * inv, v.y * inv);
        }
    }
    __syncthreads();

    for (int i = t; i < 512; i += 128)
        p.HA[b * 512 + i] = __float22half2_rn(sh.in.hid[h][i >> 5][i & 31]);
    __syncthreads();
}

// ---------------- compile-time CG product emission (verified) --------------
template <int LL>
__device__ __forceinline__ void norm_l(float2 (&hv)[16]) {
    float s = 0.f;
#pragma unroll
    for (int m = 0; m < 2 * LL + 1; ++m) {
        float2 v = hv[LL * LL + m];
        s += v.x * v.x + v.y * v.y;
    }
    float inv = 1.0f / sqrtf(s);
#pragma unroll
    for (int m = 0; m < 2 * LL + 1; ++m) {
        hv[LL * LL + m].x *= inv;
        hv[LL * LL + m].y *= inv;
    }
}

template <int L, int PS, int R, int I>
__device__ __forceinline__ void cg_term(const float2 (&hv)[16], float2& acc) {
    if constexpr (I < 7) {
        constexpr int nM = 2 * L + 1;
        constexpr int pl = R / nM, M = R % nM;
        constexpr int l1 = kP1[PS + pl], l2 = kP2[PS + pl];
        constexpr float coef = kCGC_CE.v[kCGCoff[L] + R * 7 + I];
        if constexpr (coef != 0.0f) {
            constexpr int jj = (M - L) - (I - l1) + l2;
            constexpr int s1 = l1 * l1 + I, s2 = l2 * l2 + jj;
            float2 a = hv[s1], b = hv[s2];
            acc.x += coef * (a.x * b.x - a.y * b.y);
            acc.y += coef * (a.x * b.y + a.y * b.x);
        }
        cg_term<L, PS, R, I + 1>(hv, acc);
    }
}

// Write rows of pair PL into per-pair LDS A-stage (fragment layout):
// half2 idx = (rowL>>4)*512 + coffbase + (rowL&15)*4, rowL = el*nM + M,
// coffbase = (c>>4)*256 + ((c>>2)&3)*64 + (c&3)   [verified mapping]
template <int L, int PS, int R0, int R1>
__device__ __forceinline__ void cg_rows_lds(const float2 (&hv)[16],
                                            __half2* __restrict__ As, int elemBase,
                                            int coffbase) {
    if constexpr (R0 < R1) {
        constexpr int nM = 2 * L + 1;
        constexpr int M = R0 % nM;
        float2 acc = make_float2(0.f, 0.f);
        cg_term<L, PS, R0, 0>(hv, acc);
        int rowL = elemBase + M;
        As[((rowL >> 4) << 9) + coffbase + ((rowL & 15) << 2)] = __float22half2_rn(acc);
        cg_rows_lds<L, PS, R0 + 1, R1>(hv, As, elemBase, coffbase);
    }
}

// ---------------- MFMA per pair (A from LDS, W from global) ----------------
template <int L>
__device__ __forceinline__ void mfma_pair(const _Float16* __restrict__ As,
                                          const _Float16* __restrict__ WTl, int pl,
                                          int tid, f32x4 (&acc)[2][2]) {
    constexpr int nM = 2 * L + 1, KT = kKp[L] / 32;
    const int wave = tid >> 6, lane = tid & 63;
    const int p = wave & 1, fq = wave >> 1;
    const int nt0 = 2 * p;
#pragma unroll
    for (int ktl = 0; ktl < 2; ++ktl) {
        int kt = 2 * pl + ktl;
        f16x8 w0 = *(const f16x8*)(WTl + (nt0 * KT + kt) * 512 + lane * 8);
        f16x8 w1 = *(const f16x8*)(WTl + ((nt0 + 1) * KT + kt) * 512 + lane * 8);
#pragma unroll
        for (int ji = 0; ji < 2; ++ji) {
            int j = fq + 4 * ji;
            if (j < nM) {
                f16x8 a = *(const f16x8*)(As + (j * 2 + ktl) * 512 + lane * 8);
                acc[ji][0] = __builtin_amdgcn_mfma_f32_16x16x32_f16(a, w0, acc[ji][0], 0, 0, 0);
                acc[ji][1] = __builtin_amdgcn_mfma_f32_16x16x32_f16(a, w1, acc[ji][1], 0, 0, 0);
            }
        }
    }
}

template <int L, int PS, int NP, int PL>
__device__ __forceinline__ void pair_loop(const float2 (&hv)[16], __half2* As,
                                          const _Float16* WTl, f32x4 (&acc)[2][2],
                                          int tid, int elemBase, int coffbase) {
    if constexpr (PL < NP) {
        constexpr int nM = 2 * L + 1;
        cg_rows_lds<L, PS, PL * nM, (PL + 1) * nM>(hv, As, elemBase, coffbase);
        __syncthreads();
        mfma_pair<L>((const _Float16*)As, WTl, PL, tid, acc);
        __syncthreads();
        pair_loop<L, PS, NP, PL + 1>(hv, As, WTl, acc, tid, elemBase, coffbase);
    }
}

// Epilogue: wave holds ntile-pair p for frags j = fq + 4*ji.
// D row = j*16 + kb*4 + r; col slot ar -> H col c' = ar + 16*p (half2 re,im).
template <int L>
__device__ __forceinline__ void epilogue(f32x4 (&acc)[2][2], __half2* __restrict__ Hout,
                                         int blk, int tid) {
    constexpr int nM = 2 * L + 1;
    const int wave = tid >> 6, lane = tid & 63;
    const int ar = lane & 15, kb = lane >> 4;
    const int p = wave & 1, fq = wave >> 1;
#pragma unroll
    for (int ji = 0; ji < 2; ++ji) {
        int j = fq + 4 * ji;
        if (j < nM) {
#pragma unroll
            for (int r = 0; r < 4; ++r) {
                int row = j * 16 + kb * 4 + r;
                int el = row / nM, M = row - el * nM;
                Hout[(blk * 16 + el) * 512 + (L * L + M) * 32 + ar + 16 * p] =
                    __floats2half2_rn(acc[ji][0][r], acc[ji][1][r]);
            }
        }
    }
}

template <int L, int PS, int NP>
__device__ __forceinline__ void do_L(const float2 (&hv)[16], __half2* As,
                                     const _Float16* WTl, __half2* Hout, int blk,
                                     int tid) {
    constexpr int nM = 2 * L + 1;
    f32x4 z = {0.f, 0.f, 0.f, 0.f};
    f32x4 acc[2][2] = {{z, z}, {z, z}};
    const int el = tid >> 5, c = tid & 31;
    const int elemBase = el * nM;
    const int coffbase = ((c >> 4) << 8) + (((c >> 2) & 3) << 6) + (c & 3);
    pair_loop<L, PS, NP, 0>(hv, As, WTl, acc, tid, elemBase, coffbase);
    epilogue<L>(acc, Hout, blk, tid);
}

// ---------------- final pass (4 elems per pass, verified body) -------------
__device__ __forceinline__ void final_pass(const KParams& p, int blk, int vb, int tid,
                                           ShU4& sh) {
    const int h = tid >> 7, t = tid & 127;
    const int b = blk * 16 + vb * 4 + h;
    float* shv = sh.shv[h];
    {
        int l = t >> 5, c = t & 31, off = l * l, n = 2 * l + 1;
        float s = 0.f;
        for (int m = 0; m < n; ++m) {
            float2 v = __half22float2(p.HA[b * 512 + (off + m) * 32 + c]);
            s += v.x * v.x + v.y * v.y;
        }
        shv[t] = sqrtf(s);
    }
    __syncthreads();
#pragma unroll
    for (int rr = 0; rr < 2; ++rr) {
        int j = t + rr * 128;
        float acc = p.b1[j];
        for (int i = 0; i < 128; ++i) acc += shv[i] * p.W1[i * 256 + j];
        shv[128 + j] = tanhf(acc);
    }
    __syncthreads();
    float partial = shv[128 + t] * p.W2[t] + shv[256 + t] * p.W2[t + 128];
#pragma unroll
    for (int off = 32; off > 0; off >>= 1) partial += __shfl_down(partial, off);
    if ((t & 63) == 0) shv[384 + ((t >> 6) & 1)] = partial;
    __syncthreads();
    if (t == 0) p.out[b] = shv[384] + shv[385] + p.b2[0];
    __syncthreads();
}

// ---------------- fused per-layer kernel -----------------------------------
template <int LAYER>
__global__ void __launch_bounds__(512) k_layer(KParams p) {
    __shared__ __align__(16) __half2 As[3584];  // per-pair A-stage (max L=3: 7*2*256)
    __shared__ ShU4 sh;
    const int tid = threadIdx.x;
    const int blk = blockIdx.x;

    if constexpr (LAYER == 0) {
        for (int vb = 0; vb < 4; ++vb) input_pass(p, blk, vb, tid, sh);
    }

    const __half2* Hin = (LAYER == 0) ? p.HA : p.HB;
    float2 hv[16];
    const int el = tid >> 5, c = tid & 31;
#pragma unroll
    for (int s = 0; s < 16; ++s)
        hv[s] = __half22float2(Hin[(blk * 16 + el) * 512 + s * 32 + c]);
    if constexpr (LAYER == 1) {
        norm_l<0>(hv);
        norm_l<1>(hv);
        norm_l<2>(hv);
        norm_l<3>(hv);
    }

    __half2* Hout = (LAYER == 0) ? p.HB : p.HA;
    const _Float16* WTL = (const _Float16*)p.WT + LAYER * WT_LAYER;
    do_L<0, 0, 4>(hv, As, WTL + kWToff[0], Hout, blk, tid);
    do_L<1, 4, 9>(hv, As, WTL + kWToff[1], Hout, blk, tid);
    do_L<2, 13, 11>(hv, As, WTL + kWToff[2], Hout, blk, tid);
    do_L<3, 24, 10>(hv, As, WTL + kWToff[3], Hout, blk, tid);

    if constexpr (LAYER == 1) {
        __syncthreads();
        for (int vb = 0; vb < 4; ++vb) final_pass(p, blk, vb, tid, sh);
    }
}

extern "C" void kernel_launch(void* const* d_in, const int* in_sizes, int n_in,
                              void* d_out, int out_size, void* d_ws, size_t ws_size,
                              hipStream_t stream) {
    (void)n_in;
    (void)ws_size;
    (void)out_size;
    const int B = in_sizes[0] / 32;  // part_0 is [B,1,16,2]

    char* ws = (char*)d_ws;
    __half* WTh = (__half*)ws;
    size_t off = 557056;  // 2*WT_LAYER*2 bytes
    __half2* HA = (__half2*)(ws + off);
    off += (size_t)B * 2048;
    __half2* HB = (__half2*)(ws + off);

    KParams prm;
    prm.p0 = (const float*)d_in[0];
    prm.p1 = (const float*)d_in[1];
    prm.p2 = (const float*)d_in[2];
    prm.p3 = (const float*)d_in[3];
    prm.Wi0 = (const float*)d_in[4];
    prm.Wi1 = (const float*)d_in[5];
    prm.Wi2 = (const float*)d_in[6];
    prm.Wi3 = (const float*)d_in[7];
    prm.h00 = (const float*)d_in[8];
    prm.h01 = (const float*)d_in[9];
    prm.h02 = (const float*)d_in[10];
    prm.h03 = (const float*)d_in[11];
    prm.h10 = (const float*)d_in[12];
    prm.h11 = (const float*)d_in[13];
    prm.h12 = (const float*)d_in[14];
    prm.h13 = (const float*)d_in[15];
    prm.W1 = (const float*)d_in[16];
    prm.b1 = (const float*)d_in[17];
    prm.W2 = (const float*)d_in[18];
    prm.b2 = (const float*)d_in[19];
    prm.WT = WTh;
    prm.HA = HA;
    prm.HB = HB;
    prm.out = (float*)d_out;
    prm.B = B;

    hipLaunchKernelGGL(k_wt, dim3(2 * WT_LAYER / 256), dim3(256), 0, stream,
                       prm.h00, prm.h01, prm.h02, prm.h03, prm.h10, prm.h11, prm.h12,
                       prm.h13, WTh);
    hipLaunchKernelGGL((k_layer<0>), dim3(B / 16), dim3(512), 0, stream, prm);
    hipLaunchKernelGGL((k_layer<1>), dim3(B / 16), dim3(512), 0, stream, prm);
}

// Round 12
// 124.239 us; speedup vs baseline: 1.4771x; 1.4771x over previous
//
#include <hip/hip_runtime.h>
#include <hip/hip_fp16.h>
#include <math.h>

// ---------------------------------------------------------------------------
// Spherical CNN regression forward (MAXL=3, 2 layers, TAU_IN=16, TAU_H=32).
// 5-launch pipeline (round-9 verified bulk kernels + merged front):
//   k_in_cg0:  [blocks 0..B/2)   input matmul + normalize (LDS, 2 elems/block)
//                                then per-wave L=waveid CG emission -> A tiled
//              [blocks B/2..+1088) WT realification (tiled + col-permuted)
//   k_gemm_all (layer0) -> HB      (verified round-9 kernel, 2 frags/wave)
//   k_cg_all<true> (layer1 norm+CG) -> A                (verified round-9)
//   k_gemm_all (layer1) -> HA                            (verified round-9)
//   k_final: norms + MLP -> out                          (verified round-9)
// A layout: [mt][kt][lane=(kb*16+ar)][8 halves]; WT tiled [nt][kt][lane][8],
// col-permuted so the gemm epilogue writes half2 (re,im).
// ws layout: [WT 557056 B][HA B*2048 B][HB B*2048 B][A0|A1|A2|A3]
// ---------------------------------------------------------------------------

typedef _Float16 f16x8 __attribute__((ext_vector_type(8)));
typedef float f32x4 __attribute__((ext_vector_type(4)));

constexpr int kPS[5] = {0, 4, 13, 24, 34};
constexpr unsigned char kP1[34] = {
    0, 1, 2, 3,
    0, 1, 1, 1, 2, 2, 2, 3, 3,
    0, 1, 1, 1, 2, 2, 2, 2, 3, 3, 3,
    0, 1, 1, 2, 2, 2, 3, 3, 3, 3};
constexpr unsigned char kP2[34] = {
    0, 1, 2, 3,
    1, 0, 1, 2, 1, 2, 3, 2, 3,
    2, 1, 2, 3, 0, 1, 2, 3, 1, 2, 3,
    3, 2, 3, 1, 2, 3, 0, 1, 2, 3};
constexpr int kCGCoff[5] = {0, 28, 217, 602, 1092};
constexpr int kKp[4] = {256, 576, 704, 640};         // K' = 2*NP*32 per L
constexpr int kWToff[4] = {0, 16384, 53248, 98304};  // half offsets within a layer
#define WT_LAYER 139264                               // halves per layer
#define CGC_TOTAL 1092

// ---------------- compile-time compact CG table ----------------------------
constexpr double cfact(int n) {
    double r = 1.0;
    for (int i = 2; i <= n; ++i) r *= (double)i;
    return r;
}
constexpr double csqrt(double x) {
    double g = (x > 1.0) ? x : 1.0;
    for (int it = 0; it < 64; ++it) g = 0.5 * (g + x / g);
    return g;
}
constexpr double cg_coef(int l1, int l2, int L, int m1, int m2) {
    int M = m1 + m2;
    double pre = csqrt((2.0 * L + 1.0) * cfact(l1 + l2 - L) * cfact(l1 - l2 + L) *
                       cfact(-l1 + l2 + L) / cfact(l1 + l2 + L + 1));
    pre *= csqrt(cfact(L + M) * cfact(L - M) * cfact(l1 - m1) * cfact(l1 + m1) *
                 cfact(l2 - m2) * cfact(l2 + m2));
    double s = 0.0;
    for (int k = 0; k <= l1 + l2 - L; ++k) {
        int u2 = l1 - m1 - k, u3 = l2 + m2 - k;
        int u4 = L - l2 + m1 + k, u5 = L - l1 - m2 + k;
        if (u2 < 0 || u3 < 0 || u4 < 0 || u5 < 0) continue;
        double d = cfact(k) * cfact(l1 + l2 - L - k) * cfact(u2) * cfact(u3) *
                   cfact(u4) * cfact(u5);
        s += ((k & 1) ? -1.0 : 1.0) / d;
    }
    return pre * s;
}
struct CGCTable {
    float v[CGC_TOTAL];
};
constexpr CGCTable makeCGC() {
    CGCTable T{};
    for (int t = 0; t < CGC_TOTAL; ++t) {
        int L = 0;
        while (t >= kCGCoff[L + 1]) ++L;
        int rloc = t - kCGCoff[L];
        int r = rloc / 7, i = rloc % 7;
        int nM = 2 * L + 1;
        int pl = r / nM, M = r % nM;
        int l1 = kP1[kPS[L] + pl], l2 = kP2[kPS[L] + pl];
        float val = 0.0f;
        int j = (M - L) - (i - l1) + l2;
        if (i <= 2 * l1 && j >= 0 && j <= 2 * l2)
            val = (float)cg_coef(l1, l2, L, i - l1, j - l2);
        T.v[t] = val;
    }
    return T;
}
constexpr CGCTable kCGC_CE = makeCGC();

// ---------------- compile-time CG product emission (verified) --------------
template <int LL>
__device__ __forceinline__ void norm_l(float2 (&hv)[16]) {
    float s = 0.f;
#pragma unroll
    for (int m = 0; m < 2 * LL + 1; ++m) {
        float2 v = hv[LL * LL + m];
        s += v.x * v.x + v.y * v.y;
    }
    float inv = 1.0f / sqrtf(s);
#pragma unroll
    for (int m = 0; m < 2 * LL + 1; ++m) {
        hv[LL * LL + m].x *= inv;
        hv[LL * LL + m].y *= inv;
    }
}

template <int L, int PS, int R, int I>
__device__ __forceinline__ void cg_term(const float2 (&hv)[16], float2& acc) {
    if constexpr (I < 7) {
        constexpr int nM = 2 * L + 1;
        constexpr int pl = R / nM, M = R % nM;
        constexpr int l1 = kP1[PS + pl], l2 = kP2[PS + pl];
        constexpr float coef = kCGC_CE.v[kCGCoff[L] + R * 7 + I];
        if constexpr (coef != 0.0f) {
            constexpr int jj = (M - L) - (I - l1) + l2;
            constexpr int s1 = l1 * l1 + I, s2 = l2 * l2 + jj;
            float2 a = hv[s1], b = hv[s2];
            acc.x += coef * (a.x * b.x - a.y * b.y);
            acc.y += coef * (a.x * b.y + a.y * b.x);
        }
        cg_term<L, PS, R, I + 1>(hv, acc);
    }
}

// Write rows into fragment-tiled A (verified): dst half2 idx =
// (mt*KT + 2*pl)*256 + coff + ar*4, coff = (c>>4)*256+((c>>2)&3)*64+(c&3)
template <int L, int PS, int R0, int R1>
__device__ __forceinline__ void cg_rows(const float2 (&hv)[16], __half2* __restrict__ A2,
                                        int elemBase, int coff) {
    if constexpr (R0 < R1) {
        constexpr int nM = 2 * L + 1, KT = kKp[L] / 32;
        constexpr int pl = R0 / nM, M = R0 % nM;
        float2 acc = make_float2(0.f, 0.f);
        cg_term<L, PS, R0, 0>(hv, acc);
        int row = elemBase + M;
        int mt = row >> 4, ar = row & 15;
        A2[(mt * KT + 2 * pl) * 256 + coff + ar * 4] = __float22half2_rn(acc);
        cg_rows<L, PS, R0 + 1, R1>(hv, A2, elemBase, coff);
    }
}

template <int L, int PS, int NP>
__device__ __forceinline__ void cg_emit(const float2 (&hv)[16], __half2* __restrict__ A2,
                                        int elem, int c) {
    constexpr int nM = 2 * L + 1;
    const int coff = ((c >> 4) << 8) + (((c >> 2) & 3) << 6) + (c & 3);
    cg_rows<L, PS, 0, NP * nM>(hv, A2, elem * nM, coff);
}

template <int L, int PS, int NP, bool NORM>
__device__ __forceinline__ void cg_body(const __half2* __restrict__ Hin,
                                        __half2* __restrict__ A2, int elem, int c) {
    float2 hv[16];
#pragma unroll
    for (int s = 0; s < 16; ++s) hv[s] = __half22float2(Hin[elem * 512 + s * 32 + c]);
    if constexpr (NORM) {
        norm_l<0>(hv);
        norm_l<1>(hv);
        norm_l<2>(hv);
        norm_l<3>(hv);
    }
    cg_emit<L, PS, NP>(hv, A2, elem, c);
}

// ---------------- merged front kernel: input+norm+cg0  ||  WT --------------
__global__ void __launch_bounds__(256) k_in_cg0(
    const float* __restrict__ p0, const float* __restrict__ p1,
    const float* __restrict__ p2, const float* __restrict__ p3,
    const float* __restrict__ Wi0, const float* __restrict__ Wi1,
    const float* __restrict__ Wi2, const float* __restrict__ Wi3,
    const float* __restrict__ h00, const float* __restrict__ h01,
    const float* __restrict__ h02, const float* __restrict__ h03,
    const float* __restrict__ h10, const float* __restrict__ h11,
    const float* __restrict__ h12, const float* __restrict__ h13,
    __half* __restrict__ WT, __half2* __restrict__ A0, __half2* __restrict__ A1,
    __half2* __restrict__ A2_, __half2* __restrict__ A3, int nin) {
    const int tid = threadIdx.x;
    const int bid = blockIdx.x;

    if (bid >= nin) {
        // ---- WT realification (verified mapping) ----
        int t = (bid - nin) * 256 + tid;  // [0, 2*WT_LAYER)
        int layer = t / WT_LAYER, rem = t % WT_LAYER;
        int L;
        if (rem < 16384) L = 0;
        else if (rem < 53248) L = 1;
        else if (rem < 98304) L = 2;
        else L = 3;
        int rem2 = rem - kWToff[L];
        int KT = kKp[L] / 32;
        int tile = rem2 >> 9, within = rem2 & 511;
        int lane = within >> 3, e8 = within & 7;
        int nt = tile / KT, kt = tile - nt * KT;
        int nr = lane & 15, kb = lane >> 4;
        int np = 2 * nr + (nt & 1) + 32 * (nt >> 1);  // col-perm
        int kp = kt * 32 + kb * 8 + e8;
        int q = kp >> 1, s = kp & 1, cW = np >> 1, tt = np & 1;
        const float* W = (layer == 0) ? (L == 0 ? h00 : L == 1 ? h01 : L == 2 ? h02 : h03)
                                      : (L == 0 ? h10 : L == 1 ? h11 : L == 2 ? h12 : h13);
        float wr = W[(q * 32 + cW) * 2], wi = W[(q * 32 + cW) * 2 + 1];
        float v = (tt == 0) ? (s == 0 ? wr : -wi) : (s == 0 ? wi : wr);
        WT[t] = __float2half(v);
        return;
    }

    // ---- input matmul + normalize for 2 elements (verified body) ----
    __shared__ float2 stg[2][256];
    __shared__ float2 hid[2][16][32];
    {
        const int h = tid >> 7, t = tid & 127;
        const int b = bid * 2 + h;
        for (int idx = t; idx < 256; idx += 128) {
            int slot = idx >> 4, k = idx & 15;
            int l = (slot >= 9) + (slot >= 4) + (slot >= 1);
            int m = slot - l * l;
            const float* src = (l == 0) ? p0 : (l == 1) ? p1 : (l == 2) ? p2 : p3;
            src += ((size_t)(b * (2 * l + 1) + m) * 16 + k) * 2;
            stg[h][idx] = make_float2(src[0], src[1]);
        }
    }
    __syncthreads();
    {
        const int h = tid >> 7, t = tid & 127;
#pragma unroll
        for (int r = 0; r < 4; ++r) {
            int oi = t + 128 * r;
            int slot = oi >> 5, c = oi & 31;
            int l = (slot >= 9) + (slot >= 4) + (slot >= 1);
            const float* W = (l == 0) ? Wi0 : (l == 1) ? Wi1 : (l == 2) ? Wi2 : Wi3;
            const float2* prow = &stg[h][slot * 16];
            float2 acc = make_float2(0.f, 0.f);
            for (int k = 0; k < 16; ++k) {
                float2 a = prow[k];
                float2 w = *(const float2*)(W + (k * 32 + c) * 2);
                acc.x += a.x * w.x - a.y * w.y;
                acc.y += a.x * w.y + a.y * w.x;
            }
            hid[h][slot][c] = acc;
        }
    }
    __syncthreads();
    {
        const int h = tid >> 7, t = tid & 127;
        int l = t >> 5, c = t & 31;
        int off = l * l, n = 2 * l + 1;
        float s = 0.f;
        for (int m = 0; m < n; ++m) {
            float2 v = hid[h][off + m][c];
            s += v.x * v.x + v.y * v.y;
        }
        float inv = 1.0f / sqrtf(s);
        for (int m = 0; m < n; ++m) {
            float2 v = hid[h][off + m][c];
            hid[h][off + m][c] = make_float2(v.x * inv, v.y * inv);
        }
    }
    __syncthreads();

    // ---- CG layer 0 straight from LDS: wave = L, lane halves = 2 elements --
    {
        const int wave = tid >> 6, lane = tid & 63;
        const int h = lane >> 5, c = lane & 31;
        const int elem = bid * 2 + h;
        float2 hv[16];
#pragma unroll
        for (int s = 0; s < 16; ++s) hv[s] = hid[h][s][c];
        if (wave == 0) cg_emit<0, 0, 4>(hv, A0, elem, c);
        else if (wave == 1) cg_emit<1, 4, 9>(hv, A1, elem, c);
        else if (wave == 2) cg_emit<2, 13, 11>(hv, A2_, elem, c);
        else cg_emit<3, 24, 10>(hv, A3, elem, c);
    }
}

// ---------------- CG layer-1 kernel (verified round-9) ---------------------
template <bool NORM>
__global__ void __launch_bounds__(256) k_cg_all(const __half2* __restrict__ Hin,
                                                __half2* __restrict__ A0,
                                                __half2* __restrict__ A1,
                                                __half2* __restrict__ A2_,
                                                __half2* __restrict__ A3, int nbseg) {
    const int tid = threadIdx.x;
    const int wave = tid >> 6, lane = tid & 63;
    const int c = lane & 31, h = lane >> 5;
    int bid = blockIdx.x;
    if (bid < nbseg) {
        int elem = (bid * 4 + wave) * 2 + h;
        cg_body<0, 0, 4, NORM>(Hin, A0, elem, c);
    } else if (bid < 2 * nbseg) {
        int elem = ((bid - nbseg) * 4 + wave) * 2 + h;
        cg_body<1, 4, 9, NORM>(Hin, A1, elem, c);
    } else if (bid < 3 * nbseg) {
        int elem = ((bid - 2 * nbseg) * 4 + wave) * 2 + h;
        cg_body<2, 13, 11, NORM>(Hin, A2_, elem, c);
    } else {
        int elem = ((bid - 3 * nbseg) * 4 + wave) * 2 + h;
        cg_body<3, 24, 10, NORM>(Hin, A3, elem, c);
    }
}

// ---------------- GEMM (verified round-9): tiled A x tiled WT --------------
template <int L>
__device__ __forceinline__ void gemm_body(const _Float16* __restrict__ A,
                                          const _Float16* __restrict__ WT,
                                          __half2* __restrict__ Hout, int blk, int tid) {
    constexpr int nM = 2 * L + 1, KT = kKp[L] / 32;
    const int wave = tid >> 6, lane = tid & 63;
    const int mt0 = blk * 8 + wave * 2, mt1 = mt0 + 1;
    const int ar = lane & 15, kb = lane >> 4;

    const _Float16* Ap0 = A + (size_t)(mt0 * KT) * 512 + lane * 8;
    const _Float16* Ap1 = A + (size_t)(mt1 * KT) * 512 + lane * 8;
    const _Float16* Wp = WT + lane * 8;

    f32x4 d00 = {0.f, 0.f, 0.f, 0.f}, d01 = d00, d02 = d00, d03 = d00;
    f32x4 d10 = d00, d11 = d00, d12 = d00, d13 = d00;
#pragma unroll 2
    for (int kt = 0; kt < KT; ++kt) {
        f16x8 a0 = *(const f16x8*)(Ap0 + kt * 512);
        f16x8 a1 = *(const f16x8*)(Ap1 + kt * 512);
        f16x8 w0 = *(const f16x8*)(Wp + (0 * KT + kt) * 512);
        f16x8 w1 = *(const f16x8*)(Wp + (1 * KT + kt) * 512);
        f16x8 w2 = *(const f16x8*)(Wp + (2 * KT + kt) * 512);
        f16x8 w3 = *(const f16x8*)(Wp + (3 * KT + kt) * 512);
        d00 = __builtin_amdgcn_mfma_f32_16x16x32_f16(a0, w0, d00, 0, 0, 0);
        d01 = __builtin_amdgcn_mfma_f32_16x16x32_f16(a0, w1, d01, 0, 0, 0);
        d02 = __builtin_amdgcn_mfma_f32_16x16x32_f16(a0, w2, d02, 0, 0, 0);
        d03 = __builtin_amdgcn_mfma_f32_16x16x32_f16(a0, w3, d03, 0, 0, 0);
        d10 = __builtin_amdgcn_mfma_f32_16x16x32_f16(a1, w0, d10, 0, 0, 0);
        d11 = __builtin_amdgcn_mfma_f32_16x16x32_f16(a1, w1, d11, 0, 0, 0);
        d12 = __builtin_amdgcn_mfma_f32_16x16x32_f16(a1, w2, d12, 0, 0, 0);
        d13 = __builtin_amdgcn_mfma_f32_16x16x32_f16(a1, w3, d13, 0, 0, 0);
    }

    const int rowb0 = mt0 * 16 + kb * 4, rowb1 = mt1 * 16 + kb * 4;
#pragma unroll
    for (int r = 0; r < 4; ++r) {
        int row = rowb0 + r;
        int e = row / nM, M = row - e * nM;
        int base = e * 512 + (L * L + M) * 32;
        Hout[base + ar] = __floats2half2_rn(d00[r], d01[r]);
        Hout[base + 16 + ar] = __floats2half2_rn(d02[r], d03[r]);
    }
#pragma unroll
    for (int r = 0; r < 4; ++r) {
        int row = rowb1 + r;
        int e = row / nM, M = row - e * nM;
        int base = e * 512 + (L * L + M) * 32;
        Hout[base + ar] = __floats2half2_rn(d10[r], d11[r]);
        Hout[base + 16 + ar] = __floats2half2_rn(d12[r], d13[r]);
    }
}

__global__ void __launch_bounds__(256) k_gemm_all(
    const _Float16* __restrict__ A0, const _Float16* __restrict__ A1,
    const _Float16* __restrict__ A2_, const _Float16* __restrict__ A3,
    const _Float16* __restrict__ WT, __half2* __restrict__ Hout, int nb) {
    const int tid = threadIdx.x;
    int bid = blockIdx.x;
    if (bid < nb) {
        gemm_body<0>(A0, WT + kWToff[0], Hout, bid, tid);
    } else if (bid < 4 * nb) {
        gemm_body<1>(A1, WT + kWToff[1], Hout, bid - nb, tid);
    } else if (bid < 9 * nb) {
        gemm_body<2>(A2_, WT + kWToff[2], Hout, bid - 4 * nb, tid);
    } else {
        gemm_body<3>(A3, WT + kWToff[3], Hout, bid - 9 * nb, tid);
    }
}

// ---------------- final norms + MLP (verified round-9) ---------------------
__global__ void __launch_bounds__(128) k_final(const __half2* __restrict__ H,
                                               const float* __restrict__ W1,
                                               const float* __restrict__ b1,
                                               const float* __restrict__ W2,
                                               const float* __restrict__ b2,
                                               float* __restrict__ out) {
    __shared__ float shv[392];
    const int tid = threadIdx.x, b = blockIdx.x;
    {
        int l = tid >> 5, c = tid & 31, off = l * l, n = 2 * l + 1;
        float s = 0.f;
        for (int m = 0; m < n; ++m) {
            float2 v = __half22float2(H[b * 512 + (off + m) * 32 + c]);
            s += v.x * v.x + v.y * v.y;
        }
        shv[tid] = sqrtf(s);
    }
    __syncthreads();
#pragma unroll
    for (int rr = 0; rr < 2; ++rr) {
        int j = tid + rr * 128;
        float acc = b1[j];
        for (int i = 0; i < 128; ++i) acc += shv[i] * W1[i * 256 + j];
        shv[128 + j] = tanhf(acc);
    }
    __syncthreads();
    float partial = shv[128 + tid] * W2[tid] + shv[256 + tid] * W2[tid + 128];
#pragma unroll
    for (int off = 32; off > 0; off >>= 1) partial += __shfl_down(partial, off);
    if ((tid & 63) == 0) shv[384 + (tid >> 6)] = partial;
    __syncthreads();
    if (tid == 0) out[b] = shv[384] + shv[385] + b2[0];
}

extern "C" void kernel_launch(void* const* d_in, const int* in_sizes, int n_in,
                              void* d_out, int out_size, void* d_ws, size_t ws_size,
                              hipStream_t stream) {
    (void)n_in;
    (void)ws_size;
    (void)out_size;
    const int B = in_sizes[0] / 32;  // part_0 is [B,1,16,2]

    char* ws = (char*)d_ws;
    // ws layout (bytes): WT | HA | HB | A0 | A1 | A2 | A3
    __half* WTh = (__half*)ws;
    _Float16* WTf = (_Float16*)ws;
    size_t off = 557056;  // 2*WT_LAYER*2 bytes
    __half2* HA = (__half2*)(ws + off);
    off += (size_t)B * 2048;
    __half2* HB = (__half2*)(ws + off);
    off += (size_t)B * 2048;
    __half* Ab = (__half*)(ws + off);
    size_t a0 = 0;
    size_t a1 = a0 + (size_t)B * 1 * 256;
    size_t a2 = a1 + (size_t)B * 3 * 576;
    size_t a3 = a2 + (size_t)B * 5 * 704;

    __half2* A0h = (__half2*)(Ab + a0);
    __half2* A1h = (__half2*)(Ab + a1);
    __half2* A2h = (__half2*)(Ab + a2);
    __half2* A3h = (__half2*)(Ab + a3);
    _Float16* A0f = (_Float16*)(Ab + a0);
    _Float16* A1f = (_Float16*)(Ab + a1);
    _Float16* A2f = (_Float16*)(Ab + a2);
    _Float16* A3f = (_Float16*)(Ab + a3);

    const int nin = B / 2;
    const int nbseg = B / 8, nb = B / 128;

    // ---- front: input+norm+cg0 || WT ----
    hipLaunchKernelGGL(k_in_cg0, dim3(nin + 2 * WT_LAYER / 256), dim3(256), 0, stream,
                       (const float*)d_in[0], (const float*)d_in[1],
                       (const float*)d_in[2], (const float*)d_in[3],
                       (const float*)d_in[4], (const float*)d_in[5],
                       (const float*)d_in[6], (const float*)d_in[7],
                       (const float*)d_in[8], (const float*)d_in[9],
                       (const float*)d_in[10], (const float*)d_in[11],
                       (const float*)d_in[12], (const float*)d_in[13],
                       (const float*)d_in[14], (const float*)d_in[15], WTh, A0h, A1h,
                       A2h, A3h, nin);

    // ---- layer 0 GEMM -> HB ----
    hipLaunchKernelGGL(k_gemm_all, dim3(16 * nb), dim3(256), 0, stream,
                       A0f, A1f, A2f, A3f, WTf + 0 * WT_LAYER, HB, nb);

    // ---- layer 1: CG (normalize) -> A ----
    hipLaunchKernelGGL((k_cg_all<true>), dim3(4 * nbseg), dim3(256), 0, stream, HB,
                       A0h, A1h, A2h, A3h, nbseg);

    // ---- layer 1 GEMM -> HA ----
    hipLaunchKernelGGL(k_gemm_all, dim3(16 * nb), dim3(256), 0, stream,
                       A0f, A1f, A2f, A3f, WTf + 1 * WT_LAYER, HA, nb);

    // ---- final ----
    hipLaunchKernelGGL(k_final, dim3(B), dim3(128), 0, stream, HA,
                       (const float*)d_in[16], (const float*)d_in[17],
                       (const float*)d_in[18], (const float*)d_in[19], (float*)d_out);
}